// Round 1
// baseline (156.774 us; speedup 1.0000x reference)
//
#include <hip/hip_runtime.h>
#include <hip/hip_bf16.h>
#include <stdint.h>

#define B_ 8
#define C_ 512
#define N_ 2048

typedef __bf16 bf16_t;
typedef bf16_t bf16x8 __attribute__((ext_vector_type(8)));
typedef bf16_t bf16x4 __attribute__((ext_vector_type(4)));
typedef float f32x4 __attribute__((ext_vector_type(4)));

// ---------------------------------------------------------------------------
// Cast the three 512x512 weight matrices to bf16.
// grid (256,1,3), block 256; each thread converts 4 floats.
// ---------------------------------------------------------------------------
__global__ __launch_bounds__(256) void cast_w_kernel(
    const float* __restrict__ w0, const float* __restrict__ w1,
    const float* __restrict__ w2, bf16_t* __restrict__ out)
{
    const float* src = (blockIdx.z == 0) ? w0 : ((blockIdx.z == 1) ? w1 : w2);
    bf16_t* dst = out + (size_t)blockIdx.z * (C_ * C_);
    int i = (blockIdx.x * 256 + threadIdx.x) * 4;
    float4 f = *(const float4*)(src + i);
    bf16x4 o;
    o[0] = (bf16_t)f.x; o[1] = (bf16_t)f.y; o[2] = (bf16_t)f.z; o[3] = (bf16_t)f.w;
    *(bf16x4*)(dst + i) = o;
}

// ---------------------------------------------------------------------------
// Transpose-cast: in fp32 [B][C_][N_]  ->  out bf16 [B][N_][C_]
// 64x64 tiles; grid (N_/64, C_/64, B_), block 256.
// ---------------------------------------------------------------------------
__global__ __launch_bounds__(256) void transpose_cast_kernel(
    const float* __restrict__ in, bf16_t* __restrict__ out)
{
    __shared__ bf16_t tile[64][65];
    const int b = blockIdx.z;
    const float* src = in + (size_t)b * C_ * N_;
    bf16_t* dst = out + (size_t)b * N_ * C_;
    const int n0 = blockIdx.x * 64;
    const int c0 = blockIdx.y * 64;
    const int t = threadIdx.x;

    // load: 16 lanes x float4 cover a 64-wide row; 16 rows per pass, 4 passes
    const int cx = (t & 15) * 4;   // col within tile (n-dim)
    const int ry = t >> 4;         // 0..15
#pragma unroll
    for (int r = ry; r < 64; r += 16) {
        float4 f = *(const float4*)&src[(size_t)(c0 + r) * N_ + n0 + cx];
        tile[r][cx + 0] = (bf16_t)f.x;
        tile[r][cx + 1] = (bf16_t)f.y;
        tile[r][cx + 2] = (bf16_t)f.z;
        tile[r][cx + 3] = (bf16_t)f.w;
    }
    __syncthreads();
    // store: each thread writes 4 contiguous c's (8B) per row
    const int c4 = (t & 15) * 4;   // c within tile
    const int rb = t >> 4;         // 0..15
#pragma unroll
    for (int r = rb; r < 64; r += 16) {
        bf16x4 o;
        o[0] = tile[c4 + 0][r];
        o[1] = tile[c4 + 1][r];
        o[2] = tile[c4 + 2][r];
        o[3] = tile[c4 + 3][r];
        *(bf16x4*)&dst[(size_t)(n0 + r) * C_ + c0 + c4] = o;
    }
}

// ---------------------------------------------------------------------------
// NT GEMM: C[m,n] = sum_k A[m,k] * B[n,k]   (A: [M,K] row-major, B: [N,K] row-major)
// 128x128 tile, BK=64, 256 threads (4 waves, 2x2), mfma_f32_16x16x32_bf16.
// EPI: 0 = bf16 out; 1 = bf16 out + bias[m]; 2 = bf16 out + bias[n];
//      3 = f32 out + resid (same layout as C)
// All of M, N multiples of 128; K multiple of 64 (true for every call here).
// ---------------------------------------------------------------------------
template <int EPI>
__global__ __launch_bounds__(256) void gemm_nt(
    const bf16_t* __restrict__ A, const bf16_t* __restrict__ Bm,
    void* __restrict__ Cout, const float* __restrict__ bias,
    const float* __restrict__ resid,
    int M, int Nn, int K, size_t sA, size_t sB, size_t sC)
{
    __shared__ __align__(16) bf16_t As[128 * 64];
    __shared__ __align__(16) bf16_t Bs[128 * 64];

    const int tid  = threadIdx.x;
    const int lane = tid & 63;
    const int wave = tid >> 6;
    const int wr = wave >> 1;   // wave row (0..1)
    const int wc = wave & 1;    // wave col (0..1)
    const int bz = blockIdx.z;

    const bf16_t* Ab = A + (size_t)bz * sA;
    const bf16_t* Bb = Bm + (size_t)bz * sB;
    const int m0 = blockIdx.y * 128;
    const int n0 = blockIdx.x * 128;

    f32x4 acc[4][4];
#pragma unroll
    for (int i = 0; i < 4; ++i)
#pragma unroll
        for (int j = 0; j < 4; ++j) acc[i][j] = 0.f;

    // staging decomposition: 256 threads x 16B = 4KB per pass; 4 passes per 16KB tile
    const int srow = tid >> 3;          // 0..31 (row within pass-group)
    const int scol = (tid & 7) * 8;     // element col within BK=64
    const int ldsoff = tid * 16;        // byte offset, +p*4096

    for (int kt = 0; kt < K; kt += 64) {
        const bf16_t* ga = Ab + (size_t)(m0 + srow) * K + kt + scol;
        const bf16_t* gb = Bb + (size_t)(n0 + srow) * K + kt + scol;
#pragma unroll
        for (int p = 0; p < 4; ++p) {
            __builtin_amdgcn_global_load_lds(
                (const __attribute__((address_space(1))) void*)(ga + (size_t)p * 32 * K),
                (__attribute__((address_space(3))) void*)((char*)As + ldsoff + p * 4096),
                16, 0, 0);
        }
#pragma unroll
        for (int p = 0; p < 4; ++p) {
            __builtin_amdgcn_global_load_lds(
                (const __attribute__((address_space(1))) void*)(gb + (size_t)p * 32 * K),
                (__attribute__((address_space(3))) void*)((char*)Bs + ldsoff + p * 4096),
                16, 0, 0);
        }
        __syncthreads();

#pragma unroll
        for (int kk = 0; kk < 64; kk += 32) {
            bf16x8 af[4], bfr[4];
            const int arow = wr * 64 + (lane & 15);
            const int brow = wc * 64 + (lane & 15);
            const int kcol = kk + (lane >> 4) * 8;
#pragma unroll
            for (int m = 0; m < 4; ++m)
                af[m] = *(const bf16x8*)&As[(size_t)(arow + m * 16) * 64 + kcol];
#pragma unroll
            for (int n = 0; n < 4; ++n)
                bfr[n] = *(const bf16x8*)&Bs[(size_t)(brow + n * 16) * 64 + kcol];
#pragma unroll
            for (int m = 0; m < 4; ++m)
#pragma unroll
                for (int n = 0; n < 4; ++n)
                    acc[m][n] = __builtin_amdgcn_mfma_f32_16x16x32_bf16(
                        af[m], bfr[n], acc[m][n], 0, 0, 0);
        }
        __syncthreads();
    }

    // epilogue: C/D layout col = lane&15, row = (lane>>4)*4 + j  [m89-verified]
    const int rj = (lane >> 4) * 4;
    const int cc = lane & 15;
#pragma unroll
    for (int m = 0; m < 4; ++m) {
#pragma unroll
        for (int n = 0; n < 4; ++n) {
            const int col = n0 + wc * 64 + n * 16 + cc;
            f32x4 v = acc[m][n];
#pragma unroll
            for (int j = 0; j < 4; ++j) {
                const int row = m0 + wr * 64 + m * 16 + rj + j;
                float val = v[j];
                if (EPI == 1) val += bias[row];
                if (EPI == 2) val += bias[col];
                if (EPI == 3) {
                    float* o = (float*)Cout + (size_t)bz * sC + (size_t)row * Nn + col;
                    *o = val + resid[(size_t)bz * sC + (size_t)row * Nn + col];
                } else {
                    bf16_t* o = (bf16_t*)Cout + (size_t)bz * sC + (size_t)row * Nn + col;
                    *o = (bf16_t)val;
                }
            }
        }
    }
}

// ---------------------------------------------------------------------------
extern "C" void kernel_launch(void* const* d_in, const int* in_sizes, int n_in,
                              void* d_out, int out_size, void* d_ws, size_t ws_size,
                              hipStream_t stream)
{
    (void)in_sizes; (void)n_in; (void)out_size; (void)ws_size;
    const float* q  = (const float*)d_in[0];
    const float* k  = (const float*)d_in[1];
    const float* v  = (const float*)d_in[2];
    const float* wq = (const float*)d_in[3];
    const float* bq = (const float*)d_in[4];
    const float* wk = (const float*)d_in[5];
    const float* bk = (const float*)d_in[6];
    const float* wv = (const float*)d_in[7];
    const float* bv = (const float*)d_in[8];
    float* out = (float*)d_out;

    char* ws = (char*)d_ws;
    const size_t WSZ = (size_t)C_ * C_ * 2;            // 512 KB per weight
    const size_t TSZ = (size_t)B_ * N_ * C_ * 2;       // 16 MB per tensor
    bf16_t* Wqb = (bf16_t*)(ws);
    bf16_t* Wkb = (bf16_t*)(ws + WSZ);
    bf16_t* Wvb = (bf16_t*)(ws + 2 * WSZ);
    bf16_t* T   = (bf16_t*)(ws + 3 * WSZ);             // transpose buffer (reused)
    bf16_t* Pq  = (bf16_t*)(ws + 3 * WSZ + TSZ);
    bf16_t* Pk  = (bf16_t*)(ws + 3 * WSZ + 2 * TSZ);
    bf16_t* Pv  = (bf16_t*)(ws + 3 * WSZ + 3 * TSZ);
    bf16_t* St  = (bf16_t*)(ws + 3 * WSZ + 4 * TSZ);   // 4 MB

    const dim3 blk(256);
    const size_t sBN = (size_t)N_ * C_;     // per-batch elements of [N,C]/[C,N]
    const size_t sCC = (size_t)C_ * C_;

    // 1. weights -> bf16 (order in ws: Wq, Wk, Wv)
    cast_w_kernel<<<dim3(256, 1, 3), blk, 0, stream>>>(wq, wk, wv, Wqb);

    // 2. kT = transpose(k) -> Pk = Wk * k + bk   ([C,N] bf16, bias per row)
    transpose_cast_kernel<<<dim3(N_ / 64, C_ / 64, B_), blk, 0, stream>>>(k, T);
    gemm_nt<1><<<dim3(N_ / 128, C_ / 128, B_), blk, 0, stream>>>(
        Wkb, T, (void*)Pk, bk, nullptr, C_, N_, C_, 0, sBN, sBN);

    // 3. vT -> Pv = Wv * v + bv
    transpose_cast_kernel<<<dim3(N_ / 64, C_ / 64, B_), blk, 0, stream>>>(v, T);
    gemm_nt<1><<<dim3(N_ / 128, C_ / 128, B_), blk, 0, stream>>>(
        Wvb, T, (void*)Pv, bv, nullptr, C_, N_, C_, 0, sBN, sBN);

    // 4. qT -> Pq = (Wq * q + bq)^T   ([N,C] bf16, bias per col)
    transpose_cast_kernel<<<dim3(N_ / 64, C_ / 64, B_), blk, 0, stream>>>(q, T);
    gemm_nt<2><<<dim3(C_ / 128, N_ / 128, B_), blk, 0, stream>>>(
        T, Wqb, (void*)Pq, bq, nullptr, N_, C_, C_, sBN, 0, sBN);

    // 5. St[c2,c1] = sum_n Pv[c2,n] * Pk[c1,n]   (= (Kp^T Vp)^T, bf16)
    gemm_nt<0><<<dim3(C_ / 128, C_ / 128, B_), blk, 0, stream>>>(
        Pv, Pk, (void*)St, nullptr, nullptr, C_, C_, N_, sBN, sBN, sCC);

    // 6. out[c2,n] = sum_c1 St[c2,c1] * Pq[n,c1] + q[c2,n]   (fp32, final layout)
    gemm_nt<3><<<dim3(N_ / 128, C_ / 128, B_), blk, 0, stream>>>(
        St, Pq, (void*)out, nullptr, q, C_, N_, C_, sCC, sBN, sBN);
}

// Round 2
// 139.147 us; speedup vs baseline: 1.1267x; 1.1267x over previous
//
#include <hip/hip_runtime.h>
#include <hip/hip_bf16.h>
#include <stdint.h>

#define B_ 8
#define C_ 512
#define N_ 2048

typedef __bf16 bf16_t;
typedef bf16_t bf16x8 __attribute__((ext_vector_type(8)));
typedef bf16_t bf16x4 __attribute__((ext_vector_type(4)));
typedef float f32x4 __attribute__((ext_vector_type(4)));

// ---------------------------------------------------------------------------
// Cast the three 512x512 weight matrices to bf16.
// ---------------------------------------------------------------------------
__global__ __launch_bounds__(256) void cast_w_kernel(
    const float* __restrict__ w0, const float* __restrict__ w1,
    const float* __restrict__ w2, bf16_t* __restrict__ out)
{
    const float* src = (blockIdx.z == 0) ? w0 : ((blockIdx.z == 1) ? w1 : w2);
    bf16_t* dst = out + (size_t)blockIdx.z * (C_ * C_);
    int i = (blockIdx.x * 256 + threadIdx.x) * 4;
    float4 f = *(const float4*)(src + i);
    bf16x4 o;
    o[0] = (bf16_t)f.x; o[1] = (bf16_t)f.y; o[2] = (bf16_t)f.z; o[3] = (bf16_t)f.w;
    *(bf16x4*)(dst + i) = o;
}

// ---------------------------------------------------------------------------
// Transpose-cast: in fp32 [B][C_][N_]  ->  out bf16 [B][N_][C_]
// ---------------------------------------------------------------------------
__global__ __launch_bounds__(256) void transpose_cast_kernel(
    const float* __restrict__ in, bf16_t* __restrict__ out)
{
    __shared__ bf16_t tile[64][65];
    const int b = blockIdx.z;
    const float* src = in + (size_t)b * C_ * N_;
    bf16_t* dst = out + (size_t)b * N_ * C_;
    const int n0 = blockIdx.x * 64;
    const int c0 = blockIdx.y * 64;
    const int t = threadIdx.x;

    const int cx = (t & 15) * 4;
    const int ry = t >> 4;
#pragma unroll
    for (int r = ry; r < 64; r += 16) {
        float4 f = *(const float4*)&src[(size_t)(c0 + r) * N_ + n0 + cx];
        tile[r][cx + 0] = (bf16_t)f.x;
        tile[r][cx + 1] = (bf16_t)f.y;
        tile[r][cx + 2] = (bf16_t)f.z;
        tile[r][cx + 3] = (bf16_t)f.w;
    }
    __syncthreads();
    const int c4 = (t & 15) * 4;
    const int rb = t >> 4;
#pragma unroll
    for (int r = rb; r < 64; r += 16) {
        bf16x4 o;
        o[0] = tile[c4 + 0][r];
        o[1] = tile[c4 + 1][r];
        o[2] = tile[c4 + 2][r];
        o[3] = tile[c4 + 3][r];
        *(bf16x4*)&dst[(size_t)(n0 + r) * C_ + c0 + c4] = o;
    }
}

// ---------------------------------------------------------------------------
// NT GEMM: C[m,n] = sum_k A[m,k] * B[n,k]
// 128x128 tile, BK=64, 256 threads (4 waves, 2x2), mfma_f32_16x16x32_bf16.
// EPI: 0 = bf16 out; 1 = bf16 out + bias[m]; 2 = bf16 out + bias[n];
//      3 = f32 out + resid
// SPLITS: split-K factor. blockIdx.z = batch*SPLITS + split; each split
// covers K/SPLITS of the k-range and writes partial (batch*SPLITS+split)*sC.
// ---------------------------------------------------------------------------
template <int EPI, int SPLITS>
__global__ __launch_bounds__(256) void gemm_nt(
    const bf16_t* __restrict__ A, const bf16_t* __restrict__ Bm,
    void* __restrict__ Cout, const float* __restrict__ bias,
    const float* __restrict__ resid,
    int M, int Nn, int K, size_t sA, size_t sB, size_t sC)
{
    __shared__ __align__(16) bf16_t As[128 * 64];
    __shared__ __align__(16) bf16_t Bs[128 * 64];

    const int tid  = threadIdx.x;
    const int lane = tid & 63;
    const int wave = tid >> 6;
    const int wr = wave >> 1;
    const int wc = wave & 1;
    const int bz = blockIdx.z / SPLITS;
    const int sp = blockIdx.z % SPLITS;
    const int kbeg = sp * (K / SPLITS);
    const int kend = kbeg + (K / SPLITS);

    const bf16_t* Ab = A + (size_t)bz * sA;
    const bf16_t* Bb = Bm + (size_t)bz * sB;
    const int m0 = blockIdx.y * 128;
    const int n0 = blockIdx.x * 128;

    f32x4 acc[4][4];
#pragma unroll
    for (int i = 0; i < 4; ++i)
#pragma unroll
        for (int j = 0; j < 4; ++j) acc[i][j] = 0.f;

    const int srow = tid >> 3;
    const int scol = (tid & 7) * 8;
    const int ldsoff = tid * 16;

    for (int kt = kbeg; kt < kend; kt += 64) {
        const bf16_t* ga = Ab + (size_t)(m0 + srow) * K + kt + scol;
        const bf16_t* gb = Bb + (size_t)(n0 + srow) * K + kt + scol;
#pragma unroll
        for (int p = 0; p < 4; ++p) {
            __builtin_amdgcn_global_load_lds(
                (const __attribute__((address_space(1))) void*)(ga + (size_t)p * 32 * K),
                (__attribute__((address_space(3))) void*)((char*)As + ldsoff + p * 4096),
                16, 0, 0);
        }
#pragma unroll
        for (int p = 0; p < 4; ++p) {
            __builtin_amdgcn_global_load_lds(
                (const __attribute__((address_space(1))) void*)(gb + (size_t)p * 32 * K),
                (__attribute__((address_space(3))) void*)((char*)Bs + ldsoff + p * 4096),
                16, 0, 0);
        }
        __syncthreads();

#pragma unroll
        for (int kk = 0; kk < 64; kk += 32) {
            bf16x8 af[4], bfr[4];
            const int arow = wr * 64 + (lane & 15);
            const int brow = wc * 64 + (lane & 15);
            const int kcol = kk + (lane >> 4) * 8;
#pragma unroll
            for (int m = 0; m < 4; ++m)
                af[m] = *(const bf16x8*)&As[(size_t)(arow + m * 16) * 64 + kcol];
#pragma unroll
            for (int n = 0; n < 4; ++n)
                bfr[n] = *(const bf16x8*)&Bs[(size_t)(brow + n * 16) * 64 + kcol];
#pragma unroll
            for (int m = 0; m < 4; ++m)
#pragma unroll
                for (int n = 0; n < 4; ++n)
                    acc[m][n] = __builtin_amdgcn_mfma_f32_16x16x32_bf16(
                        af[m], bfr[n], acc[m][n], 0, 0, 0);
        }
        __syncthreads();
    }

    // epilogue: C/D layout col = lane&15, row = (lane>>4)*4 + j
    const int rj = (lane >> 4) * 4;
    const int cc = lane & 15;
#pragma unroll
    for (int m = 0; m < 4; ++m) {
#pragma unroll
        for (int n = 0; n < 4; ++n) {
            const int col = n0 + wc * 64 + n * 16 + cc;
            f32x4 v = acc[m][n];
#pragma unroll
            for (int j = 0; j < 4; ++j) {
                const int row = m0 + wr * 64 + m * 16 + rj + j;
                float val = v[j];
                if (EPI == 1) val += bias[row];
                if (EPI == 2) val += bias[col];
                if (EPI == 3) {
                    float* o = (float*)Cout + (size_t)bz * sC + (size_t)row * Nn + col;
                    *o = val + resid[(size_t)bz * sC + (size_t)row * Nn + col];
                } else {
                    bf16_t* o = (bf16_t*)Cout + (size_t)blockIdx.z * sC + (size_t)row * Nn + col;
                    *o = (bf16_t)val;
                }
            }
        }
    }
}

// ---------------------------------------------------------------------------
// Sum 4 split-K bf16 partials -> bf16 St.
// Pt: [B_][4][C_*C_], St: [B_][C_*C_]. 8 elems/thread.
// ---------------------------------------------------------------------------
__global__ __launch_bounds__(256) void reduce_splitk_kernel(
    const bf16_t* __restrict__ Pt, bf16_t* __restrict__ St)
{
    const size_t sCC = (size_t)C_ * C_;
    size_t idx = ((size_t)blockIdx.x * 256 + threadIdx.x) * 8;
    size_t b = idx / sCC;          // power-of-two -> shift
    size_t r = idx - b * sCC;
    const bf16_t* base = Pt + (b * 4) * sCC + r;
    float acc[8];
#pragma unroll
    for (int j = 0; j < 8; ++j) acc[j] = 0.f;
#pragma unroll
    for (int s = 0; s < 4; ++s) {
        bf16x8 pv = *(const bf16x8*)(base + (size_t)s * sCC);
#pragma unroll
        for (int j = 0; j < 8; ++j) acc[j] += (float)pv[j];
    }
    bf16x8 o;
#pragma unroll
    for (int j = 0; j < 8; ++j) o[j] = (bf16_t)acc[j];
    *(bf16x8*)(St + idx) = o;
}

// ---------------------------------------------------------------------------
extern "C" void kernel_launch(void* const* d_in, const int* in_sizes, int n_in,
                              void* d_out, int out_size, void* d_ws, size_t ws_size,
                              hipStream_t stream)
{
    (void)in_sizes; (void)n_in; (void)out_size; (void)ws_size;
    const float* q  = (const float*)d_in[0];
    const float* k  = (const float*)d_in[1];
    const float* v  = (const float*)d_in[2];
    const float* wq = (const float*)d_in[3];
    const float* bq = (const float*)d_in[4];
    const float* wk = (const float*)d_in[5];
    const float* bk = (const float*)d_in[6];
    const float* wv = (const float*)d_in[7];
    const float* bv = (const float*)d_in[8];
    float* out = (float*)d_out;

    char* ws = (char*)d_ws;
    const size_t WSZ = (size_t)C_ * C_ * 2;            // 512 KB per weight
    const size_t TSZ = (size_t)B_ * N_ * C_ * 2;       // 16.78 MB per tensor
    bf16_t* Wqb = (bf16_t*)(ws);
    bf16_t* Wkb = (bf16_t*)(ws + WSZ);
    bf16_t* Wvb = (bf16_t*)(ws + 2 * WSZ);
    bf16_t* T   = (bf16_t*)(ws + 3 * WSZ);             // transpose buf; dead after
                                                       // step 4 -> reused for split-K
                                                       // partials (8*4*512*512*2B = TSZ)
    bf16_t* Pq  = (bf16_t*)(ws + 3 * WSZ + TSZ);
    bf16_t* Pk  = (bf16_t*)(ws + 3 * WSZ + 2 * TSZ);
    bf16_t* Pv  = (bf16_t*)(ws + 3 * WSZ + 3 * TSZ);
    bf16_t* St  = (bf16_t*)(ws + 3 * WSZ + 4 * TSZ);   // 4 MB

    const dim3 blk(256);
    const size_t sBN = (size_t)N_ * C_;
    const size_t sCC = (size_t)C_ * C_;

    // 1. weights -> bf16
    cast_w_kernel<<<dim3(256, 1, 3), blk, 0, stream>>>(wq, wk, wv, Wqb);

    // 2. kT -> Pk = Wk * k + bk   ([C,N] bf16, bias per row)
    transpose_cast_kernel<<<dim3(N_ / 64, C_ / 64, B_), blk, 0, stream>>>(k, T);
    gemm_nt<1, 1><<<dim3(N_ / 128, C_ / 128, B_), blk, 0, stream>>>(
        Wkb, T, (void*)Pk, bk, nullptr, C_, N_, C_, 0, sBN, sBN);

    // 3. vT -> Pv = Wv * v + bv
    transpose_cast_kernel<<<dim3(N_ / 64, C_ / 64, B_), blk, 0, stream>>>(v, T);
    gemm_nt<1, 1><<<dim3(N_ / 128, C_ / 128, B_), blk, 0, stream>>>(
        Wvb, T, (void*)Pv, bv, nullptr, C_, N_, C_, 0, sBN, sBN);

    // 4. qT -> Pq = (Wq * q + bq)^T   ([N,C] bf16, bias per col)
    transpose_cast_kernel<<<dim3(N_ / 64, C_ / 64, B_), blk, 0, stream>>>(q, T);
    gemm_nt<2, 1><<<dim3(C_ / 128, N_ / 128, B_), blk, 0, stream>>>(
        T, Wqb, (void*)Pq, bq, nullptr, N_, C_, C_, sBN, 0, sBN);

    // 5. split-K (S=4): T[b][s] = partial over k-range s of Pv * Pk^T, then
    //    St[c2,c1] = sum_s T[b][s][c2,c1]. 512 wg instead of 128 (was 5% occ).
    gemm_nt<0, 4><<<dim3(C_ / 128, C_ / 128, B_ * 4), blk, 0, stream>>>(
        Pv, Pk, (void*)T, nullptr, nullptr, C_, C_, N_, sBN, sBN, sCC);
    reduce_splitk_kernel<<<dim3((B_ * sCC) / (256 * 8)), blk, 0, stream>>>(T, St);

    // 6. out[c2,n] = sum_c1 St[c2,c1] * Pq[n,c1] + q[c2,n]
    gemm_nt<3, 1><<<dim3(N_ / 128, C_ / 128, B_), blk, 0, stream>>>(
        St, Pq, (void*)out, nullptr, q, C_, N_, C_, sCC, sBN, sBN);
}

// Round 3
// 136.009 us; speedup vs baseline: 1.1527x; 1.0231x over previous
//
#include <hip/hip_runtime.h>
#include <hip/hip_bf16.h>
#include <stdint.h>

#define B_ 8
#define C_ 512
#define N_ 2048

typedef __bf16 bf16_t;
typedef bf16_t bf16x8 __attribute__((ext_vector_type(8)));
typedef bf16_t bf16x4 __attribute__((ext_vector_type(4)));
typedef float f32x4 __attribute__((ext_vector_type(4)));

// ---------------------------------------------------------------------------
// Cast two 512x512 weight matrices to bf16 (Wk, Wv). grid (256,1,2).
// ---------------------------------------------------------------------------
__global__ __launch_bounds__(256) void cast_w_kernel(
    const float* __restrict__ w0, const float* __restrict__ w1,
    bf16_t* __restrict__ out)
{
    const float* src = (blockIdx.z == 0) ? w0 : w1;
    bf16_t* dst = out + (size_t)blockIdx.z * (C_ * C_);
    int i = (blockIdx.x * 256 + threadIdx.x) * 4;
    float4 f = *(const float4*)(src + i);
    bf16x4 o;
    o[0] = (bf16_t)f.x; o[1] = (bf16_t)f.y; o[2] = (bf16_t)f.z; o[3] = (bf16_t)f.w;
    *(bf16x4*)(dst + i) = o;
}

// ---------------------------------------------------------------------------
// Transpose-cast Wq: in fp32 [C][C] -> out bf16 [C][C] with out[i][c]=in[c][i].
// grid (C/64, C/64), block 256.
// ---------------------------------------------------------------------------
__global__ __launch_bounds__(256) void transpose_cast_w_kernel(
    const float* __restrict__ in, bf16_t* __restrict__ out)
{
    __shared__ bf16_t tile[64][65];
    const int i0 = blockIdx.x * 64;   // output row dim (i)
    const int c0 = blockIdx.y * 64;   // input row dim (c)
    const int t = threadIdx.x;
    const int cx = (t & 15) * 4;
    const int ry = t >> 4;
#pragma unroll
    for (int r = ry; r < 64; r += 16) {
        float4 f = *(const float4*)&in[(size_t)(c0 + r) * C_ + i0 + cx];
        tile[r][cx + 0] = (bf16_t)f.x;
        tile[r][cx + 1] = (bf16_t)f.y;
        tile[r][cx + 2] = (bf16_t)f.z;
        tile[r][cx + 3] = (bf16_t)f.w;
    }
    __syncthreads();
    const int c4 = (t & 15) * 4;
    const int rb = t >> 4;
#pragma unroll
    for (int r = rb; r < 64; r += 16) {
        bf16x4 o;
        o[0] = tile[c4 + 0][r];
        o[1] = tile[c4 + 1][r];
        o[2] = tile[c4 + 2][r];
        o[3] = tile[c4 + 3][r];
        *(bf16x4*)&out[(size_t)(i0 + r) * C_ + c0 + c4] = o;
    }
}

// ---------------------------------------------------------------------------
// Fused-transpose projection GEMM:
//   P[c,n] = sum_i A[c,i] * X[b,i,n]   A bf16 [M,K] row-major (global_load_lds),
//                                      X fp32 [K,Nn] per batch, cast+transposed
//                                      into swizzled LDS during staging.
// EPI 1: bf16 out + bias[row].  EPI 3: fp32 out + bias[bz*bstride+row] + resid.
// Tile 128(m) x 128(n), BK=64, 256 threads (2x2 waves).
//
// Bs layout: byte off(n,i) = n*128 + ((2i) ^ g(n)), g(n)=((n^(n>>3))&7)<<4.
//  - writes: b32 of rows (i,i+1) -> bank (i/2)^4*chunk(n): 2-way across wave.
//  - reads: bf16x8 at 16B-aligned (2*kcol)^g(row): 8 chunks x 2 lanes: 2-way.
// ---------------------------------------------------------------------------
template <int EPI>
__global__ __launch_bounds__(256) void proj_gemm(
    const bf16_t* __restrict__ A, const float* __restrict__ X,
    void* __restrict__ Cout, const float* __restrict__ bias,
    const float* __restrict__ resid,
    int K, int Nn, size_t sAb, size_t sX, size_t sC, int bstride)
{
    __shared__ __align__(16) bf16_t As[128 * 64];
    __shared__ __align__(16) char  Bs[128 * 128];

    const int tid  = threadIdx.x;
    const int lane = tid & 63;
    const int wave = tid >> 6;
    const int wr = wave >> 1;
    const int wc = wave & 1;
    const int bz = blockIdx.z;
    const int m0 = blockIdx.y * 128;
    const int n0 = blockIdx.x * 128;

    const bf16_t* Ab = A + (size_t)bz * sAb;
    const float*  Xb = X + (size_t)bz * sX;

    f32x4 acc[4][4];
#pragma unroll
    for (int i = 0; i < 4; ++i)
#pragma unroll
        for (int j = 0; j < 4; ++j) acc[i][j] = 0.f;

    // A staging (linear, global_load_lds)
    const int srow = tid >> 3;
    const int scol = (tid & 7) * 8;
    const int ldsoff = tid * 16;

    // B staging coords: per pass, wave covers i in [16p,16p+16) x n quarter
    const int sa  = lane >> 3;             // 0..7 -> i pair 2*sa
    const int snl = wave * 32 + (lane & 7) * 4;  // n position (4 floats)

    for (int kt = 0; kt < K; kt += 64) {
        const bf16_t* ga = Ab + (size_t)(m0 + srow) * K + kt + scol;
#pragma unroll
        for (int p = 0; p < 4; ++p) {
            __builtin_amdgcn_global_load_lds(
                (const __attribute__((address_space(1))) void*)(ga + (size_t)p * 32 * K),
                (__attribute__((address_space(3))) void*)((char*)As + ldsoff + p * 4096),
                16, 0, 0);
        }
#pragma unroll
        for (int p = 0; p < 4; ++p) {
            const int iL = 16 * p + 2 * sa;                 // even local i
            const float* g0 = Xb + (size_t)(kt + iL) * Nn + n0 + snl;
            float4 f0 = *(const float4*)g0;
            float4 f1 = *(const float4*)(g0 + Nn);
#pragma unroll
            for (int j = 0; j < 4; ++j) {
                const int n = snl + j;
                const int g = ((n ^ (n >> 3)) & 7) << 4;
                const int off = n * 128 + ((2 * iL) ^ g);
                union { bf16_t h[2]; uint32_t u; } pk;
                pk.h[0] = (bf16_t)((&f0.x)[j]);
                pk.h[1] = (bf16_t)((&f1.x)[j]);
                *(uint32_t*)(Bs + off) = pk.u;
            }
        }
        __syncthreads();

#pragma unroll
        for (int kk = 0; kk < 64; kk += 32) {
            bf16x8 af[4], bfr[4];
            const int arow = wr * 64 + (lane & 15);
            const int brow0 = wc * 64 + (lane & 15);
            const int kcol = kk + (lane >> 4) * 8;
#pragma unroll
            for (int m = 0; m < 4; ++m)
                af[m] = *(const bf16x8*)&As[(size_t)(arow + m * 16) * 64 + kcol];
#pragma unroll
            for (int n = 0; n < 4; ++n) {
                const int row = brow0 + n * 16;
                const int g = ((row ^ (row >> 3)) & 7) << 4;
                bfr[n] = *(const bf16x8*)(Bs + row * 128 + ((2 * kcol) ^ g));
            }
#pragma unroll
            for (int m = 0; m < 4; ++m)
#pragma unroll
                for (int n = 0; n < 4; ++n)
                    acc[m][n] = __builtin_amdgcn_mfma_f32_16x16x32_bf16(
                        af[m], bfr[n], acc[m][n], 0, 0, 0);
        }
        __syncthreads();
    }

    const int rj = (lane >> 4) * 4;
    const int cc = lane & 15;
#pragma unroll
    for (int m = 0; m < 4; ++m) {
#pragma unroll
        for (int n = 0; n < 4; ++n) {
            const int col = n0 + wc * 64 + n * 16 + cc;
            f32x4 v = acc[m][n];
#pragma unroll
            for (int j = 0; j < 4; ++j) {
                const int row = m0 + wr * 64 + m * 16 + rj + j;
                float val = v[j] + bias[bz * bstride + row];
                if (EPI == 3) {
                    float* o = (float*)Cout + (size_t)bz * sC + (size_t)row * Nn + col;
                    *o = val + resid[(size_t)bz * sX + (size_t)row * Nn + col];
                } else {
                    bf16_t* o = (bf16_t*)Cout + (size_t)bz * sC + (size_t)row * Nn + col;
                    *o = (bf16_t)val;
                }
            }
        }
    }
}

// ---------------------------------------------------------------------------
// NT bf16 GEMM with split-K (unchanged machinery from round 2), EPI=0 only.
// ---------------------------------------------------------------------------
template <int SPLITS>
__global__ __launch_bounds__(256) void gemm_nt(
    const bf16_t* __restrict__ A, const bf16_t* __restrict__ Bm,
    bf16_t* __restrict__ Cout,
    int M, int Nn, int K, size_t sA, size_t sB, size_t sC)
{
    __shared__ __align__(16) bf16_t As[128 * 64];
    __shared__ __align__(16) bf16_t Bs[128 * 64];

    const int tid  = threadIdx.x;
    const int lane = tid & 63;
    const int wave = tid >> 6;
    const int wr = wave >> 1;
    const int wc = wave & 1;
    const int bz = blockIdx.z / SPLITS;
    const int sp = blockIdx.z % SPLITS;
    const int kbeg = sp * (K / SPLITS);
    const int kend = kbeg + (K / SPLITS);

    const bf16_t* Ab = A + (size_t)bz * sA;
    const bf16_t* Bb = Bm + (size_t)bz * sB;
    const int m0 = blockIdx.y * 128;
    const int n0 = blockIdx.x * 128;

    f32x4 acc[4][4];
#pragma unroll
    for (int i = 0; i < 4; ++i)
#pragma unroll
        for (int j = 0; j < 4; ++j) acc[i][j] = 0.f;

    const int srow = tid >> 3;
    const int scol = (tid & 7) * 8;
    const int ldsoff = tid * 16;

    for (int kt = kbeg; kt < kend; kt += 64) {
        const bf16_t* ga = Ab + (size_t)(m0 + srow) * K + kt + scol;
        const bf16_t* gb = Bb + (size_t)(n0 + srow) * K + kt + scol;
#pragma unroll
        for (int p = 0; p < 4; ++p) {
            __builtin_amdgcn_global_load_lds(
                (const __attribute__((address_space(1))) void*)(ga + (size_t)p * 32 * K),
                (__attribute__((address_space(3))) void*)((char*)As + ldsoff + p * 4096),
                16, 0, 0);
        }
#pragma unroll
        for (int p = 0; p < 4; ++p) {
            __builtin_amdgcn_global_load_lds(
                (const __attribute__((address_space(1))) void*)(gb + (size_t)p * 32 * K),
                (__attribute__((address_space(3))) void*)((char*)Bs + ldsoff + p * 4096),
                16, 0, 0);
        }
        __syncthreads();

#pragma unroll
        for (int kk = 0; kk < 64; kk += 32) {
            bf16x8 af[4], bfr[4];
            const int arow = wr * 64 + (lane & 15);
            const int brow = wc * 64 + (lane & 15);
            const int kcol = kk + (lane >> 4) * 8;
#pragma unroll
            for (int m = 0; m < 4; ++m)
                af[m] = *(const bf16x8*)&As[(size_t)(arow + m * 16) * 64 + kcol];
#pragma unroll
            for (int n = 0; n < 4; ++n)
                bfr[n] = *(const bf16x8*)&Bs[(size_t)(brow + n * 16) * 64 + kcol];
#pragma unroll
            for (int m = 0; m < 4; ++m)
#pragma unroll
                for (int n = 0; n < 4; ++n)
                    acc[m][n] = __builtin_amdgcn_mfma_f32_16x16x32_bf16(
                        af[m], bfr[n], acc[m][n], 0, 0, 0);
        }
        __syncthreads();
    }

    const int rj = (lane >> 4) * 4;
    const int cc = lane & 15;
#pragma unroll
    for (int m = 0; m < 4; ++m) {
#pragma unroll
        for (int n = 0; n < 4; ++n) {
            const int col = n0 + wc * 64 + n * 16 + cc;
            f32x4 v = acc[m][n];
#pragma unroll
            for (int j = 0; j < 4; ++j) {
                const int row = m0 + wr * 64 + m * 16 + rj + j;
                Cout[(size_t)blockIdx.z * sC + (size_t)row * Nn + col] = (bf16_t)v[j];
            }
        }
    }
}

// ---------------------------------------------------------------------------
// Sum 4 split-K bf16 partials -> bf16. Pt: [B_][4][C_*C_], Out: [B_][C_*C_].
// ---------------------------------------------------------------------------
__global__ __launch_bounds__(256) void reduce_splitk_kernel(
    const bf16_t* __restrict__ Pt, bf16_t* __restrict__ Out)
{
    const size_t sCC = (size_t)C_ * C_;
    size_t idx = ((size_t)blockIdx.x * 256 + threadIdx.x) * 8;
    size_t b = idx / sCC;
    size_t r = idx - b * sCC;
    const bf16_t* base = Pt + (b * 4) * sCC + r;
    float acc[8];
#pragma unroll
    for (int j = 0; j < 8; ++j) acc[j] = 0.f;
#pragma unroll
    for (int s = 0; s < 4; ++s) {
        bf16x8 pv = *(const bf16x8*)(base + (size_t)s * sCC);
#pragma unroll
        for (int j = 0; j < 8; ++j) acc[j] += (float)pv[j];
    }
    bf16x8 o;
#pragma unroll
    for (int j = 0; j < 8; ++j) o[j] = (bf16_t)acc[j];
    *(bf16x8*)(Out + idx) = o;
}

// ---------------------------------------------------------------------------
// h[b][c] = sum_c1 St[b][c,c1] * bq[c1].  grid (B_), block 256, 2 rows/thread.
// ---------------------------------------------------------------------------
__global__ __launch_bounds__(256) void compute_h_kernel(
    const bf16_t* __restrict__ St, const float* __restrict__ bq,
    float* __restrict__ h)
{
    const int b = blockIdx.x;
    const int c = threadIdx.x * 2;
#pragma unroll
    for (int rr = 0; rr < 2; ++rr) {
        const bf16_t* row = St + ((size_t)b * C_ + c + rr) * C_;
        float acc = 0.f;
        for (int j = 0; j < C_; j += 8) {
            bf16x8 vv = *(const bf16x8*)(row + j);
#pragma unroll
            for (int t = 0; t < 8; ++t) acc += (float)vv[t] * bq[j + t];
        }
        h[b * C_ + c + rr] = acc;
    }
}

// ---------------------------------------------------------------------------
extern "C" void kernel_launch(void* const* d_in, const int* in_sizes, int n_in,
                              void* d_out, int out_size, void* d_ws, size_t ws_size,
                              hipStream_t stream)
{
    (void)in_sizes; (void)n_in; (void)out_size; (void)ws_size;
    const float* q  = (const float*)d_in[0];
    const float* k  = (const float*)d_in[1];
    const float* v  = (const float*)d_in[2];
    const float* wq = (const float*)d_in[3];
    const float* bq = (const float*)d_in[4];
    const float* wk = (const float*)d_in[5];
    const float* bk = (const float*)d_in[6];
    const float* wv = (const float*)d_in[7];
    const float* bv = (const float*)d_in[8];
    float* out = (float*)d_out;

    char* ws = (char*)d_ws;
    const size_t WSZ = (size_t)C_ * C_ * 2;            // 512 KB
    const size_t TSZ = (size_t)B_ * N_ * C_ * 2;       // 16.78 MB
    const size_t SCZ = (size_t)B_ * C_ * C_ * 2;       // 4.19 MB
    bf16_t* Wkb  = (bf16_t*)(ws);
    bf16_t* Wvb  = (bf16_t*)(ws + WSZ);
    bf16_t* WqTb = (bf16_t*)(ws + 2 * WSZ);
    bf16_t* Pk   = (bf16_t*)(ws + 3 * WSZ);
    bf16_t* Pv   = (bf16_t*)(ws + 3 * WSZ + TSZ);
    bf16_t* Stp  = (bf16_t*)(ws + 3 * WSZ + 2 * TSZ);  // split-K partials (St)
    bf16_t* Hp   = (bf16_t*)(ws + 3 * WSZ + 3 * TSZ);  // split-K partials (H)
    bf16_t* St   = (bf16_t*)(ws + 3 * WSZ + 4 * TSZ);
    bf16_t* HT   = (bf16_t*)(ws + 3 * WSZ + 4 * TSZ + SCZ);
    float*  hb   = (float*)(ws + 3 * WSZ + 4 * TSZ + 2 * SCZ);

    const dim3 blk(256);
    const size_t sBN = (size_t)N_ * C_;
    const size_t sCC = (size_t)C_ * C_;

    // 1. Wk, Wv -> bf16; WqT = Wq^T bf16
    cast_w_kernel<<<dim3(256, 1, 2), blk, 0, stream>>>(wk, wv, Wkb);
    transpose_cast_w_kernel<<<dim3(C_ / 64, C_ / 64), blk, 0, stream>>>(wq, WqTb);

    // 2. Pk = Wk * k + bk  (fused transpose-cast of k), bf16 [C,N]
    proj_gemm<1><<<dim3(N_ / 128, C_ / 128, B_), blk, 0, stream>>>(
        Wkb, k, (void*)Pk, bk, nullptr, C_, N_, 0, sBN, sBN, 0);

    // 3. Pv = Wv * v + bv
    proj_gemm<1><<<dim3(N_ / 128, C_ / 128, B_), blk, 0, stream>>>(
        Wvb, v, (void*)Pv, bv, nullptr, C_, N_, 0, sBN, sBN, 0);

    // 4. St[c,c'] = sum_n Pv[c,n] * Pk[c',n]  (split-K 4 + reduce), bf16 [C,C]
    gemm_nt<4><<<dim3(C_ / 128, C_ / 128, B_ * 4), blk, 0, stream>>>(
        Pv, Pk, Stp, C_, C_, N_, sBN, sBN, sCC);
    reduce_splitk_kernel<<<dim3((B_ * sCC) / (256 * 8)), blk, 0, stream>>>(Stp, St);

    // 5. HT[c,i] = sum_c' St[c,c'] * WqT[i,c']  (split-K 4 + reduce), bf16 [C,C]
    gemm_nt<4><<<dim3(C_ / 128, C_ / 128, B_ * 4), blk, 0, stream>>>(
        St, WqTb, Hp, C_, C_, C_, sCC, 0, sCC);
    reduce_splitk_kernel<<<dim3((B_ * sCC) / (256 * 8)), blk, 0, stream>>>(Hp, HT);

    // 6. h[b][c] = St[b][c,:] . bq
    compute_h_kernel<<<dim3(B_), blk, 0, stream>>>(St, bq, hb);

    // 7. out[c,n] = sum_i HT[c,i] * q[i,n] + h[c] + q[c,n]   (fp32, final layout)
    proj_gemm<3><<<dim3(N_ / 128, C_ / 128, B_), blk, 0, stream>>>(
        HT, q, (void*)out, hb, q, C_, N_, sCC, sBN, sBN, C_);
}